// Round 1
// baseline (279.370 us; speedup 1.0000x reference)
//
#include <hip/hip_runtime.h>
#include <cstdint>
#include <cstddef>

#define NFEATS 128
#define NHIDS  128
#define NOUT   64
#define SB     256    // nodes per bucket (dst >> 8)
#define CHUNK  4096   // edges per chunk in the radix partition

using bf16x8 = __attribute__((ext_vector_type(8))) short;
using f32x4  = __attribute__((ext_vector_type(4))) float;
using u32x4  = __attribute__((ext_vector_type(4))) unsigned int;

__device__ inline unsigned short f2bf(float f) {           // round-to-nearest-even
    union { float f; unsigned int u; } v; v.f = f;
    unsigned int r = (v.u + 0x7FFFu + ((v.u >> 16) & 1u)) >> 16;
    return (unsigned short)r;
}
__device__ inline float bflo(unsigned int u) { return __uint_as_float(u << 16); }
__device__ inline float bfhi(unsigned int u) { return __uint_as_float(u & 0xFFFF0000u); }

// ---------------------------------------------------------------------------
// Edge-index dtype detection (int64 vs int32). flag=1 -> int32.
// ---------------------------------------------------------------------------
__global__ void detect_kernel(const void* p, int* flag, long long n_nodes) {
    const long long* q = (const long long*)p;
    long long v = q[threadIdx.x];
    int bad = (v < 0 || v >= n_nodes) ? 1 : 0;
    unsigned long long m = __ballot(bad);
    if (threadIdx.x == 0) *flag = (m != 0ULL) ? 1 : 0;
}

// ---------------------------------------------------------------------------
// Phase 1a: per-(chunk,bucket) histogram. histT[b*nch + c].
// ---------------------------------------------------------------------------
__global__ void hist_kernel(const void* __restrict__ edges, const int* __restrict__ flag,
                            int* __restrict__ histT, int ne, int nch, int nbkt) {
    __shared__ int h[1024];
    int c = blockIdx.x, t = threadIdx.x;              // blockDim = 512
    for (int i = t; i < nbkt; i += 512) h[i] = 0;
    __syncthreads();
    int beg = c * CHUNK, end = min(ne, beg + CHUNK);
    bool is32 = (*flag != 0);
    for (int i = beg + t; i < end; i += 512) {
        int d = is32 ? ((const int*)edges)[ne + i]
                     : (int)((const long long*)edges)[ne + i];
        atomicAdd(&h[d >> 8], 1);
    }
    __syncthreads();
    for (int i = t; i < nbkt; i += 512)
        histT[i * nch + c] = h[i];
}

// ---------------------------------------------------------------------------
// Exclusive scan over histT (m = nbkt*nch elements) -> chunk_base
// ---------------------------------------------------------------------------
__global__ void scan_block(const int* __restrict__ v, int* __restrict__ incl,
                           int* __restrict__ partial, int n) {
    __shared__ int sh[256];
    int t = threadIdx.x;
    int i = blockIdx.x * 256 + t;
    sh[t] = (i < n) ? v[i] : 0;
    __syncthreads();
    for (int off = 1; off < 256; off <<= 1) {
        int add = (t >= off) ? sh[t - off] : 0;
        __syncthreads();
        sh[t] += add;
        __syncthreads();
    }
    if (i < n) incl[i] = sh[t];
    if (t == 255) partial[blockIdx.x] = sh[255];
}

__global__ void scan_partials(int* partial, int nb) {
    __shared__ int sh[512];
    __shared__ int carry;
    int t = threadIdx.x;
    if (t == 0) carry = 0;
    __syncthreads();
    for (int base = 0; base < nb; base += 512) {
        int idx = base + t;
        sh[t] = (idx < nb) ? partial[idx] : 0;
        __syncthreads();
        for (int off = 1; off < 512; off <<= 1) {
            int add = (t >= off) ? sh[t - off] : 0;
            __syncthreads();
            sh[t] += add;
            __syncthreads();
        }
        int excl = carry + ((t == 0) ? 0 : sh[t - 1]);
        if (idx < nb) partial[idx] = excl;
        __syncthreads();
        if (t == 0) carry += sh[511];
        __syncthreads();
    }
}

__global__ void finalize_scan(const int* __restrict__ incl, const int* __restrict__ v,
                              const int* __restrict__ partial,
                              int* __restrict__ excl, int m) {
    int i = blockIdx.x * blockDim.x + threadIdx.x;
    if (i < m) excl[i] = partial[i >> 8] + incl[i] - v[i];
}

// ---------------------------------------------------------------------------
// Phase 1b: re-read chunk, LDS-cursor placement into precomputed per-
// (chunk,bucket) contiguous ranges. rec = (src << 8) | (dst & 255).
// ---------------------------------------------------------------------------
__global__ void scatter_chunks(const void* __restrict__ edges, const int* __restrict__ flag,
                               const int* __restrict__ chunk_base,
                               unsigned int* __restrict__ ebuf,
                               int ne, int nch, int nbkt) {
    __shared__ int cur[1024];
    int c = blockIdx.x, t = threadIdx.x;              // blockDim = 512
    for (int i = t; i < nbkt; i += 512) cur[i] = chunk_base[i * nch + c];
    __syncthreads();
    int beg = c * CHUNK, end = min(ne, beg + CHUNK);
    bool is32 = (*flag != 0);
    for (int i = beg + t; i < end; i += 512) {
        int s, d;
        if (is32) {
            s = ((const int*)edges)[i];
            d = ((const int*)edges)[ne + i];
        } else {
            s = (int)((const long long*)edges)[i];
            d = (int)((const long long*)edges)[ne + i];
        }
        int pos = atomicAdd(&cur[d >> 8], 1);
        ebuf[pos] = ((unsigned int)s << 8) | (unsigned int)(d & (SB - 1));
    }
}

// ---------------------------------------------------------------------------
// Phase 2: one block per bucket. LDS degree histogram + LDS scan ->
// row_ptr, dinv, CU-local scatter of csr_src.
// ---------------------------------------------------------------------------
__global__ void bucket_finalize(const unsigned int* __restrict__ ebuf,
                                const int* __restrict__ chunk_base,
                                int* __restrict__ row_ptr, float* __restrict__ dinv,
                                int* __restrict__ csr_src,
                                int n, int e, int nch, int nbkt) {
    __shared__ int deg[SB];
    __shared__ int incl[SB];
    __shared__ int cur[SB];
    int b = blockIdx.x, t = threadIdx.x;              // blockDim = SB = 256
    int node0 = b * SB;
    int nn = min(SB, n - node0);
    int base = chunk_base[b * nch];
    int bend = (b == nbkt - 1) ? e : chunk_base[(b + 1) * nch];

    deg[t] = 0;
    __syncthreads();
    for (int i = base + t; i < bend; i += SB)
        atomicAdd(&deg[ebuf[i] & (SB - 1)], 1);
    __syncthreads();

    incl[t] = deg[t];
    __syncthreads();
    for (int off = 1; off < SB; off <<= 1) {
        int add = (t >= off) ? incl[t - off] : 0;
        __syncthreads();
        incl[t] += add;
        __syncthreads();
    }
    int lrow = base + incl[t] - deg[t];
    cur[t] = lrow;
    if (t < nn) {
        row_ptr[node0 + t] = lrow;
        dinv[node0 + t]    = rsqrtf((float)(deg[t] + 1));
    }
    if (b == nbkt - 1 && t == 0) row_ptr[n] = e;
    __syncthreads();

    for (int i = base + t; i < bend; i += SB) {
        unsigned int r = ebuf[i];
        int pos = atomicAdd(&cur[r & (SB - 1)], 1);
        csr_src[pos] = (int)(r >> 8);
    }
}

// ---------------------------------------------------------------------------
// Pack BOTH weights into MFMA B-fragment order in global memory.
// ---------------------------------------------------------------------------
__global__ void w_pack(const float* __restrict__ W1, unsigned short* __restrict__ Wf1,
                       const float* __restrict__ W2, unsigned short* __restrict__ Wf2) {
    int i = blockIdx.x * blockDim.x + threadIdx.x;
    if (i < 128 * 128) {                               // W1: [128][128]
        int k = i >> 7, n = i & 127;
        Wf1[(((k >> 3) * 128) + n) * 8 + (k & 7)] = f2bf(W1[i]);
    }
    if (i < 128 * 64) {                                // W2: [128][64]
        int k = i >> 6, n = i & 63;
        Wf2[(((k >> 3) * 64) + n) * 8 + (k & 7)] = f2bf(W2[i]);
    }
}

// ---------------------------------------------------------------------------
// MFMA GEMM: hs[r][c] = bf16( dinv[r] * sum_k X[r][k] * W[k][c] )
// ---------------------------------------------------------------------------
template <int NC, bool F32IN>
__launch_bounds__(256)
__global__ void gemm_mfma(const void* __restrict__ Xin,
                          const unsigned short* __restrict__ Wf,
                          const float* __restrict__ dinv,
                          unsigned short* __restrict__ hs, int nrows) {
    constexpr int K = 128;
    __shared__ __align__(16) unsigned short Xl[16 * 128 * 8];   // 32 KB

    const int tid  = threadIdx.x;
    const int row0 = blockIdx.x * 128;

    for (int i = tid; i < 128 * 32; i += 256) {        // stage X tile
        int r  = i >> 5;
        int c4 = i & 31;
        int gr = row0 + r;
        ushort4 v = make_ushort4(0, 0, 0, 0);
        if (gr < nrows) {
            if (F32IN) {
                float4 f = ((const float4*)((const float*)Xin + (size_t)gr * K))[c4];
                v.x = f2bf(f.x); v.y = f2bf(f.y); v.z = f2bf(f.z); v.w = f2bf(f.w);
            } else {
                v = ((const ushort4*)((const unsigned short*)Xin + (size_t)gr * K))[c4];
            }
        }
        int k   = c4 * 4;
        int grp = k >> 3;                              // kt*4 + q
        int j0  = k & 7;                               // 0 or 4
        *(ushort4*)(Xl + ((size_t)grp * 128 + r) * 8 + j0) = v;
    }
    __syncthreads();

    const int wv   = tid >> 6;
    const int lane = tid & 63;
    const int m    = lane & 15;
    const int q    = lane >> 4;

    bf16x8 af[2][4];
#pragma unroll
    for (int h = 0; h < 2; ++h)
#pragma unroll
        for (int kt = 0; kt < 4; ++kt)
            af[h][kt] = *(const bf16x8*)(Xl + (((kt * 4 + q) * 128) + h * 64 + wv * 16 + m) * 8);

    int   rbase[2];
    float dv[2][4];
#pragma unroll
    for (int h = 0; h < 2; ++h) {
        rbase[h] = row0 + h * 64 + wv * 16 + q * 4;
#pragma unroll
        for (int i = 0; i < 4; ++i)
            dv[h][i] = (rbase[h] + i < nrows) ? dinv[rbase[h] + i] : 0.f;
    }

#pragma unroll
    for (int nt = 0; nt < NC / 16; ++nt) {
        bf16x8 bfr[4];
#pragma unroll
        for (int kt = 0; kt < 4; ++kt)
            bfr[kt] = *(const bf16x8*)(Wf + (((size_t)(kt * 4 + q) * NC) + nt * 16 + m) * 8);
#pragma unroll
        for (int h = 0; h < 2; ++h) {
            f32x4 acc = {0.f, 0.f, 0.f, 0.f};
#pragma unroll
            for (int kt = 0; kt < 4; ++kt)
                acc = __builtin_amdgcn_mfma_f32_16x16x32_bf16(af[h][kt], bfr[kt], acc, 0, 0, 0);
#pragma unroll
            for (int i = 0; i < 4; ++i) {
                int g = rbase[h] + i;
                if (g < nrows)
                    hs[(size_t)g * NC + nt * 16 + m] = f2bf(acc[i] * dv[h][i]);
            }
        }
    }
}

// ---------------------------------------------------------------------------
// CSR gather-reduce + epilogue, bf16 features (fp32 accumulate).
// R10 form: inline-asm 16-deep gathers (forced MLP — compiler was sinking
// loads: VGPR_Count=32 proved <=4 in flight), one csr_src dword per lane
// per 16-edge chunk (was 8 redundant dword loads per 8-edge batch),
// __shfl broadcast, counted vmcnt leaves next chunk's csr load in flight.
// Accumulation order per feature is unchanged (ascending edge order).
// ---------------------------------------------------------------------------
template <int F, bool RELU, bool OUTBF>
__launch_bounds__(256)
__global__ void aggregate_bf16(const int* __restrict__ row_ptr,
                               const int* __restrict__ csr_src,
                               const uint4* __restrict__ hsu,
                               const float* __restrict__ dinv,
                               const float* __restrict__ b,
                               void* __restrict__ out, int n) {
    constexpr int TPN  = F / 8;          // lanes per node (16 / 8)
    constexpr int NPB  = 256 / TPN;      // nodes per block (16 / 32)
    constexpr int CH   = 16;             // edges per pipelined chunk
    constexpr int NCSR = CH / TPN;       // csr loads/lane/chunk (1 / 2)
    int node = blockIdx.x * NPB + threadIdx.x / TPN;
    int t    = threadIdx.x % TPN;
    if (node >= n) return;
    const int lane = threadIdx.x & 63;
    const int gb   = lane & ~(TPN - 1);  // group base lane within wave

    uint4 u = hsu[(size_t)node * TPN + t];           // self-loop term
    float a[8];
    a[0] = bflo(u.x); a[1] = bfhi(u.x); a[2] = bflo(u.y); a[3] = bfhi(u.y);
    a[4] = bflo(u.z); a[5] = bfhi(u.z); a[6] = bflo(u.w); a[7] = bfhi(u.w);

    int beg = row_ptr[node], end = row_ptr[node + 1];

    if (beg < end) {
        const u32x4* hb = (const u32x4*)hsu;
        u32x4 v[CH];
        int sva, svb;
        int base = beg;

        // prologue: issue csr chunk0 (one distinct dword per lane), drain
        {
            const int* pc0 = csr_src + min(base + t, end - 1);
            asm volatile("global_load_dword %0, %1, off" : "=&v"(sva) : "v"(pc0));
            if (NCSR == 2) {
                const int* pc1 = csr_src + min(base + TPN + t, end - 1);
                asm volatile("global_load_dword %0, %1, off" : "=&v"(svb) : "v"(pc1));
            }
        }
        asm volatile("s_waitcnt vmcnt(0)");
        __builtin_amdgcn_sched_barrier(0);

        while (true) {
            int rem = min(CH, end - base);

            // broadcast src ids, issue 16 asm gathers back-to-back (16-deep)
#pragma unroll
            for (int j = 0; j < CH; ++j) {
                int jj = min(j, rem - 1);            // clamp tail to a valid row
                int sj;
                if (TPN == 16) {
                    sj = __shfl(sva, gb + jj, 64);
                } else {
                    int s0 = __shfl(sva, gb + (jj & 7), 64);
                    int s1 = __shfl(svb, gb + (jj & 7), 64);
                    sj = (jj < 8) ? s0 : s1;
                }
                const u32x4* p = hb + (size_t)sj * TPN + t;
                asm volatile("global_load_dwordx4 %0, %1, off" : "=&v"(v[j]) : "v"(p));
            }

            int  nbase = base + CH;
            bool more  = nbase < end;
            if (more) {                               // next chunk's csr: issue now
                const int* pc0 = csr_src + min(nbase + t, end - 1);
                asm volatile("global_load_dword %0, %1, off" : "=&v"(sva) : "v"(pc0));
                if (NCSR == 2) {
                    const int* pc1 = csr_src + min(nbase + TPN + t, end - 1);
                    asm volatile("global_load_dword %0, %1, off" : "=&v"(svb) : "v"(pc1));
                }
                // wait gathers only; leave csr load(s) in flight
                if (NCSR == 1) asm volatile("s_waitcnt vmcnt(1)");
                else           asm volatile("s_waitcnt vmcnt(2)");
            } else {
                asm volatile("s_waitcnt vmcnt(0)");
            }
            __builtin_amdgcn_sched_barrier(0);

            // accumulate (ascending edge order — numerically identical)
#pragma unroll
            for (int j = 0; j < CH; ++j) {
                if (j < rem) {
                    unsigned int x0 = v[j][0], x1 = v[j][1], x2 = v[j][2], x3 = v[j][3];
                    a[0] += bflo(x0); a[1] += bfhi(x0);
                    a[2] += bflo(x1); a[3] += bfhi(x1);
                    a[4] += bflo(x2); a[5] += bfhi(x2);
                    a[6] += bflo(x3); a[7] += bfhi(x3);
                }
            }

            if (!more) break;
            base = nbase;
            asm volatile("s_waitcnt vmcnt(0)");      // csr for next chunk ready
            __builtin_amdgcn_sched_barrier(0);
        }
    }

    float dvn = dinv[node];
    float4 b0 = ((const float4*)b)[2 * t];
    float4 b1 = ((const float4*)b)[2 * t + 1];
    float o[8];
    o[0] = a[0] * dvn + b0.x; o[1] = a[1] * dvn + b0.y;
    o[2] = a[2] * dvn + b0.z; o[3] = a[3] * dvn + b0.w;
    o[4] = a[4] * dvn + b1.x; o[5] = a[5] * dvn + b1.y;
    o[6] = a[6] * dvn + b1.z; o[7] = a[7] * dvn + b1.w;
    if (RELU) {
#pragma unroll
        for (int j = 0; j < 8; ++j) o[j] = fmaxf(o[j], 0.f);
    }
    if (OUTBF) {
        uint4 ov;
        ov.x = (unsigned int)f2bf(o[0]) | ((unsigned int)f2bf(o[1]) << 16);
        ov.y = (unsigned int)f2bf(o[2]) | ((unsigned int)f2bf(o[3]) << 16);
        ov.z = (unsigned int)f2bf(o[4]) | ((unsigned int)f2bf(o[5]) << 16);
        ov.w = (unsigned int)f2bf(o[6]) | ((unsigned int)f2bf(o[7]) << 16);
        ((uint4*)out)[(size_t)node * TPN + t] = ov;
    } else {
        float4* op = (float4*)out + (size_t)node * (F / 4) + 2 * t;
        op[0] = make_float4(o[0], o[1], o[2], o[3]);
        op[1] = make_float4(o[4], o[5], o[6], o[7]);
    }
}

// ---------------------------------------------------------------------------
extern "C" void kernel_launch(void* const* d_in, const int* in_sizes, int n_in,
                              void* d_out, int out_size, void* d_ws, size_t ws_size,
                              hipStream_t stream) {
    const void*  edge = d_in[0];
    const float* x    = (const float*)d_in[1];
    const float* W1   = (const float*)d_in[2];
    const float* b1   = (const float*)d_in[3];
    const float* W2   = (const float*)d_in[4];
    const float* b2   = (const float*)d_in[5];
    float* out = (float*)d_out;

    const int E    = in_sizes[0] / 2;
    const int N    = in_sizes[1] / NFEATS;
    const int NBKT = (N + SB - 1) / SB;        // 391
    const int NCH  = (E + CHUNK - 1) / CHUNK;  // 391
    const int M    = NBKT * NCH;               // histogram matrix size

    char* w = (char*)d_ws;
    auto carve = [&](size_t bytes) { void* p = w; w += (bytes + 255) & ~(size_t)255; return p; };
    int*            flag       = (int*)           carve(256);
    int*            histT      = (int*)           carve(sizeof(int) * (size_t)M);
    int*            incl       = (int*)           carve(sizeof(int) * (size_t)M);
    int*            partial    = (int*)           carve(sizeof(int) * 4096);
    int*            chunk_base = (int*)           carve(sizeof(int) * (size_t)M);
    int*            row_ptr    = (int*)           carve(sizeof(int) * ((size_t)N + 1));
    float*          dinv       = (float*)         carve(sizeof(float) * (size_t)N);
    unsigned int*   ebuf       = (unsigned int*)  carve(sizeof(int) * (size_t)E);
    int*            csr_src    = (int*)           carve(sizeof(int) * (size_t)E);
    unsigned short* Wf1        = (unsigned short*)carve(2 * (size_t)NFEATS * NHIDS);
    unsigned short* Wf2        = (unsigned short*)carve(2 * (size_t)NHIDS * NOUT);
    unsigned short* hs1        = (unsigned short*)carve(2 * (size_t)N * NHIDS);
    unsigned short* h1         = (unsigned short*)carve(2 * (size_t)N * NHIDS);
    unsigned short* hs2        = (unsigned short*)carve(2 * (size_t)N * NOUT);

    const int B   = 256;
    const int nbS = (M + 255) / 256;           // scan blocks over histogram

    detect_kernel<<<1, 64, 0, stream>>>(edge, flag, (long long)N);

    // CSR build: chunk histograms -> scan -> LDS-cursor partition -> finalize
    hist_kernel<<<NCH, 512, 0, stream>>>(edge, flag, histT, E, NCH, NBKT);
    scan_block<<<nbS, 256, 0, stream>>>(histT, incl, partial, M);
    scan_partials<<<1, 512, 0, stream>>>(partial, nbS);
    finalize_scan<<<nbS, 256, 0, stream>>>(incl, histT, partial, chunk_base, M);
    scatter_chunks<<<NCH, 512, 0, stream>>>(edge, flag, chunk_base, ebuf, E, NCH, NBKT);
    bucket_finalize<<<NBKT, SB, 0, stream>>>(ebuf, chunk_base, row_ptr, dinv, csr_src,
                                             N, E, NCH, NBKT);

    // pack both weights into B-frag order (one launch)
    w_pack<<<(128 * 128 + B - 1) / B, B, 0, stream>>>(W1, Wf1, W2, Wf2);

    // ---- layer 1 ----
    gemm_mfma<NHIDS, true><<<(N + 127) / 128, B, 0, stream>>>(x, Wf1, dinv, hs1, N);
    {
        constexpr int NPB = 256 / (NHIDS / 8);   // 16 nodes per block
        aggregate_bf16<NHIDS, true, true><<<(N + NPB - 1) / NPB, B, 0, stream>>>(
            row_ptr, csr_src, (const uint4*)hs1, dinv, b1, h1, N);
    }

    // ---- layer 2 ----
    gemm_mfma<NOUT, false><<<(N + 127) / 128, B, 0, stream>>>(h1, Wf2, dinv, hs2, N);
    {
        constexpr int NPB = 256 / (NOUT / 8);    // 32 nodes per block
        aggregate_bf16<NOUT, false, false><<<(N + NPB - 1) / NPB, B, 0, stream>>>(
            row_ptr, csr_src, (const uint4*)hs2, dinv, b2, out, N);
    }
}

// Round 2
// 251.970 us; speedup vs baseline: 1.1087x; 1.1087x over previous
//
#include <hip/hip_runtime.h>
#include <cstdint>
#include <cstddef>

#define NFEATS 128
#define NHIDS  128
#define NOUT   64
#define SB     256    // nodes per bucket (dst >> 8)
#define CHUNK  4096   // edges per chunk in the radix partition

using bf16x8 = __attribute__((ext_vector_type(8))) short;
using f32x4  = __attribute__((ext_vector_type(4))) float;
using u32x4  = __attribute__((ext_vector_type(4))) unsigned int;

__device__ inline unsigned short f2bf(float f) {           // round-to-nearest-even
    union { float f; unsigned int u; } v; v.f = f;
    unsigned int r = (v.u + 0x7FFFu + ((v.u >> 16) & 1u)) >> 16;
    return (unsigned short)r;
}
__device__ inline float bflo(unsigned int u) { return __uint_as_float(u << 16); }
__device__ inline float bfhi(unsigned int u) { return __uint_as_float(u & 0xFFFF0000u); }

// ---------------------------------------------------------------------------
// Edge-index dtype detection (int64 vs int32). flag=1 -> int32.
// ---------------------------------------------------------------------------
__global__ void detect_kernel(const void* p, int* flag, long long n_nodes) {
    const long long* q = (const long long*)p;
    long long v = q[threadIdx.x];
    int bad = (v < 0 || v >= n_nodes) ? 1 : 0;
    unsigned long long m = __ballot(bad);
    if (threadIdx.x == 0) *flag = (m != 0ULL) ? 1 : 0;
}

// ---------------------------------------------------------------------------
// Phase 1a: per-(chunk,bucket) histogram. histT[b*nch + c].
// ---------------------------------------------------------------------------
__global__ void hist_kernel(const void* __restrict__ edges, const int* __restrict__ flag,
                            int* __restrict__ histT, int ne, int nch, int nbkt) {
    __shared__ int h[1024];
    int c = blockIdx.x, t = threadIdx.x;              // blockDim = 512
    for (int i = t; i < nbkt; i += 512) h[i] = 0;
    __syncthreads();
    int beg = c * CHUNK, end = min(ne, beg + CHUNK);
    bool is32 = (*flag != 0);
    for (int i = beg + t; i < end; i += 512) {
        int d = is32 ? ((const int*)edges)[ne + i]
                     : (int)((const long long*)edges)[ne + i];
        atomicAdd(&h[d >> 8], 1);
    }
    __syncthreads();
    for (int i = t; i < nbkt; i += 512)
        histT[i * nch + c] = h[i];
}

// ---------------------------------------------------------------------------
// Exclusive scan over histT (m = nbkt*nch elements) -> chunk_base
// ---------------------------------------------------------------------------
__global__ void scan_block(const int* __restrict__ v, int* __restrict__ incl,
                           int* __restrict__ partial, int n) {
    __shared__ int sh[256];
    int t = threadIdx.x;
    int i = blockIdx.x * 256 + t;
    sh[t] = (i < n) ? v[i] : 0;
    __syncthreads();
    for (int off = 1; off < 256; off <<= 1) {
        int add = (t >= off) ? sh[t - off] : 0;
        __syncthreads();
        sh[t] += add;
        __syncthreads();
    }
    if (i < n) incl[i] = sh[t];
    if (t == 255) partial[blockIdx.x] = sh[255];
}

__global__ void scan_partials(int* partial, int nb) {
    __shared__ int sh[512];
    __shared__ int carry;
    int t = threadIdx.x;
    if (t == 0) carry = 0;
    __syncthreads();
    for (int base = 0; base < nb; base += 512) {
        int idx = base + t;
        sh[t] = (idx < nb) ? partial[idx] : 0;
        __syncthreads();
        for (int off = 1; off < 512; off <<= 1) {
            int add = (t >= off) ? sh[t - off] : 0;
            __syncthreads();
            sh[t] += add;
            __syncthreads();
        }
        int excl = carry + ((t == 0) ? 0 : sh[t - 1]);
        if (idx < nb) partial[idx] = excl;
        __syncthreads();
        if (t == 0) carry += sh[511];
        __syncthreads();
    }
}

__global__ void finalize_scan(const int* __restrict__ incl, const int* __restrict__ v,
                              const int* __restrict__ partial,
                              int* __restrict__ excl, int m) {
    int i = blockIdx.x * blockDim.x + threadIdx.x;
    if (i < m) excl[i] = partial[i >> 8] + incl[i] - v[i];
}

// ---------------------------------------------------------------------------
// Phase 1b: re-read chunk, IN-LDS bucket sort, then bucket-sorted coalesced
// global writes (R11: old version did 4B fully-uncoalesced scatter -> ~64
// lines/wave-store, ~100 MB effective write traffic for 6.4 MB payload.
// Now: local hist -> local scan -> LDS scatter -> sequential write where
// consecutive threads hit consecutive addresses within each ~10-record
// bucket run). Requires nbkt <= 512 (here 391).
// ---------------------------------------------------------------------------
__global__ void scatter_chunks(const void* __restrict__ edges, const int* __restrict__ flag,
                               const int* __restrict__ chunk_base,
                               unsigned int* __restrict__ ebuf,
                               int ne, int nch, int nbkt) {
    __shared__ int cnt[512];
    __shared__ int cursor[512];
    __shared__ int delta[512];
    __shared__ unsigned int   srt[CHUNK];            // 16 KB
    __shared__ unsigned short bkl[CHUNK];            // 8 KB
    int c = blockIdx.x, t = threadIdx.x;              // blockDim = 512
    if (t < nbkt) cnt[t] = 0;
    int cb = (t < nbkt) ? chunk_base[t * nch + c] : 0;
    __syncthreads();

    int beg = c * CHUNK, end = min(ne, beg + CHUNK);
    int nloc = end - beg;
    bool is32 = (*flag != 0);

    unsigned int rec[8];
    int bk[8];
#pragma unroll
    for (int r = 0; r < 8; ++r) {
        int i = beg + t + r * 512;
        bk[r] = -1;
        if (i < end) {
            int s, d;
            if (is32) {
                s = ((const int*)edges)[i];
                d = ((const int*)edges)[ne + i];
            } else {
                s = (int)((const long long*)edges)[i];
                d = (int)((const long long*)edges)[ne + i];
            }
            rec[r] = ((unsigned int)s << 8) | (unsigned int)(d & (SB - 1));
            bk[r]  = d >> 8;
            atomicAdd(&cnt[bk[r]], 1);
        }
    }
    __syncthreads();

    // 512-wide inclusive scan of per-bucket counts
    int v0 = (t < nbkt) ? cnt[t] : 0;
    cursor[t] = v0;
    __syncthreads();
    for (int off = 1; off < 512; off <<= 1) {
        int add = (t >= off) ? cursor[t - off] : 0;
        __syncthreads();
        cursor[t] += add;
        __syncthreads();
    }
    int incl = cursor[t];
    __syncthreads();
    int lb = incl - v0;                               // exclusive (local base)
    cursor[t] = lb;                                   // running local cursor
    if (t < nbkt) delta[t] = cb - lb;                 // global = delta[bkt] + localpos
    __syncthreads();

    // local scatter into bucket-sorted LDS order
#pragma unroll
    for (int r = 0; r < 8; ++r) {
        if (bk[r] >= 0) {
            int pos = atomicAdd(&cursor[bk[r]], 1);
            srt[pos] = rec[r];
            bkl[pos] = (unsigned short)bk[r];
        }
    }
    __syncthreads();

    // coalesced-ish writes: consecutive i -> consecutive addrs within runs
    for (int i = t; i < nloc; i += 512)
        ebuf[delta[bkl[i]] + i] = srt[i];
}

// ---------------------------------------------------------------------------
// Phase 2: one block per bucket. LDS degree histogram + LDS scan ->
// row_ptr, dinv, CU-local scatter of csr_src.
// ---------------------------------------------------------------------------
__global__ void bucket_finalize(const unsigned int* __restrict__ ebuf,
                                const int* __restrict__ chunk_base,
                                int* __restrict__ row_ptr, float* __restrict__ dinv,
                                int* __restrict__ csr_src,
                                int n, int e, int nch, int nbkt) {
    __shared__ int deg[SB];
    __shared__ int incl[SB];
    __shared__ int cur[SB];
    int b = blockIdx.x, t = threadIdx.x;              // blockDim = SB = 256
    int node0 = b * SB;
    int nn = min(SB, n - node0);
    int base = chunk_base[b * nch];
    int bend = (b == nbkt - 1) ? e : chunk_base[(b + 1) * nch];

    deg[t] = 0;
    __syncthreads();
    for (int i = base + t; i < bend; i += SB)
        atomicAdd(&deg[ebuf[i] & (SB - 1)], 1);
    __syncthreads();

    incl[t] = deg[t];
    __syncthreads();
    for (int off = 1; off < SB; off <<= 1) {
        int add = (t >= off) ? incl[t - off] : 0;
        __syncthreads();
        incl[t] += add;
        __syncthreads();
    }
    int lrow = base + incl[t] - deg[t];
    cur[t] = lrow;
    if (t < nn) {
        row_ptr[node0 + t] = lrow;
        dinv[node0 + t]    = rsqrtf((float)(deg[t] + 1));
    }
    if (b == nbkt - 1 && t == 0) row_ptr[n] = e;
    __syncthreads();

    for (int i = base + t; i < bend; i += SB) {
        unsigned int r = ebuf[i];
        int pos = atomicAdd(&cur[r & (SB - 1)], 1);
        csr_src[pos] = (int)(r >> 8);
    }
}

// ---------------------------------------------------------------------------
// Pack BOTH weights into MFMA B-fragment order in global memory.
// ---------------------------------------------------------------------------
__global__ void w_pack(const float* __restrict__ W1, unsigned short* __restrict__ Wf1,
                       const float* __restrict__ W2, unsigned short* __restrict__ Wf2) {
    int i = blockIdx.x * blockDim.x + threadIdx.x;
    if (i < 128 * 128) {                               // W1: [128][128]
        int k = i >> 7, n = i & 127;
        Wf1[(((k >> 3) * 128) + n) * 8 + (k & 7)] = f2bf(W1[i]);
    }
    if (i < 128 * 64) {                                // W2: [128][64]
        int k = i >> 6, n = i & 63;
        Wf2[(((k >> 3) * 64) + n) * 8 + (k & 7)] = f2bf(W2[i]);
    }
}

// ---------------------------------------------------------------------------
// MFMA GEMM: hs[r][c] = bf16( dinv[r] * sum_k X[r][k] * W[k][c] )
// ---------------------------------------------------------------------------
template <int NC, bool F32IN>
__launch_bounds__(256)
__global__ void gemm_mfma(const void* __restrict__ Xin,
                          const unsigned short* __restrict__ Wf,
                          const float* __restrict__ dinv,
                          unsigned short* __restrict__ hs, int nrows) {
    constexpr int K = 128;
    __shared__ __align__(16) unsigned short Xl[16 * 128 * 8];   // 32 KB

    const int tid  = threadIdx.x;
    const int row0 = blockIdx.x * 128;

    for (int i = tid; i < 128 * 32; i += 256) {        // stage X tile
        int r  = i >> 5;
        int c4 = i & 31;
        int gr = row0 + r;
        ushort4 v = make_ushort4(0, 0, 0, 0);
        if (gr < nrows) {
            if (F32IN) {
                float4 f = ((const float4*)((const float*)Xin + (size_t)gr * K))[c4];
                v.x = f2bf(f.x); v.y = f2bf(f.y); v.z = f2bf(f.z); v.w = f2bf(f.w);
            } else {
                v = ((const ushort4*)((const unsigned short*)Xin + (size_t)gr * K))[c4];
            }
        }
        int k   = c4 * 4;
        int grp = k >> 3;                              // kt*4 + q
        int j0  = k & 7;                               // 0 or 4
        *(ushort4*)(Xl + ((size_t)grp * 128 + r) * 8 + j0) = v;
    }
    __syncthreads();

    const int wv   = tid >> 6;
    const int lane = tid & 63;
    const int m    = lane & 15;
    const int q    = lane >> 4;

    bf16x8 af[2][4];
#pragma unroll
    for (int h = 0; h < 2; ++h)
#pragma unroll
        for (int kt = 0; kt < 4; ++kt)
            af[h][kt] = *(const bf16x8*)(Xl + (((kt * 4 + q) * 128) + h * 64 + wv * 16 + m) * 8);

    int   rbase[2];
    float dv[2][4];
#pragma unroll
    for (int h = 0; h < 2; ++h) {
        rbase[h] = row0 + h * 64 + wv * 16 + q * 4;
#pragma unroll
        for (int i = 0; i < 4; ++i)
            dv[h][i] = (rbase[h] + i < nrows) ? dinv[rbase[h] + i] : 0.f;
    }

#pragma unroll
    for (int nt = 0; nt < NC / 16; ++nt) {
        bf16x8 bfr[4];
#pragma unroll
        for (int kt = 0; kt < 4; ++kt)
            bfr[kt] = *(const bf16x8*)(Wf + (((size_t)(kt * 4 + q) * NC) + nt * 16 + m) * 8);
#pragma unroll
        for (int h = 0; h < 2; ++h) {
            f32x4 acc = {0.f, 0.f, 0.f, 0.f};
#pragma unroll
            for (int kt = 0; kt < 4; ++kt)
                acc = __builtin_amdgcn_mfma_f32_16x16x32_bf16(af[h][kt], bfr[kt], acc, 0, 0, 0);
#pragma unroll
            for (int i = 0; i < 4; ++i) {
                int g = rbase[h] + i;
                if (g < nrows)
                    hs[(size_t)g * NC + nt * 16 + m] = f2bf(acc[i] * dv[h][i]);
            }
        }
    }
}

// ---------------------------------------------------------------------------
// FUSED layer-1 aggregate + layer-2 GEMM.  One block = 16 nodes, 16 lanes
// per node.  CSR gather-reduce (16-deep asm pipeline, proven equal-speed),
// epilogue: h1 = bf16(relu(a*dinv + b1)) kept in LDS (bit-identical to the
// old stored h1), transpose via padded 16x136 tile, 4 MFMAs/wave against
// pre-packed Wf2 B-frags (same kt order as gemm_mfma -> bit-identical hs2),
// cooperative coalesced 2 KB store.  Eliminates h1 (51.2 MB traffic) and
// the gemm2 launch.
// ---------------------------------------------------------------------------
__launch_bounds__(256)
__global__ void aggregate_fused_l1(const int* __restrict__ row_ptr,
                                   const int* __restrict__ csr_src,
                                   const uint4* __restrict__ hsu,
                                   const float* __restrict__ dinv,
                                   const float* __restrict__ b,
                                   const unsigned short* __restrict__ Wf2,
                                   unsigned short* __restrict__ hs2, int n) {
    constexpr int TPN = 16;              // lanes per node
    constexpr int NPB = 16;              // nodes per block
    constexpr int CH  = 16;              // edges per pipelined chunk

    __shared__ __align__(16) unsigned short h1t[16 * 136];   // padded: 272 B/row
    __shared__ float dl[16];
    __shared__ __align__(16) unsigned short outt[16 * 64];   // 2 KB

    const int node0 = blockIdx.x * NPB;
    const int nl    = threadIdx.x / TPN;              // local node 0..15
    const int t     = threadIdx.x % TPN;
    const int node  = min(node0 + nl, n - 1);         // clamp (barriers below)
    const int lane  = threadIdx.x & 63;
    const int gb    = lane & ~(TPN - 1);              // group base lane in wave

    uint4 u = hsu[(size_t)node * TPN + t];            // self-loop term
    float a[8];
    a[0] = bflo(u.x); a[1] = bfhi(u.x); a[2] = bflo(u.y); a[3] = bfhi(u.y);
    a[4] = bflo(u.z); a[5] = bfhi(u.z); a[6] = bflo(u.w); a[7] = bfhi(u.w);

    int beg = row_ptr[node], end = row_ptr[node + 1];

    if (beg < end) {
        const u32x4* hb = (const u32x4*)hsu;
        u32x4 v[CH];
        int sva;
        int base = beg;

        {   // prologue: issue csr chunk0 (one distinct dword per lane), drain
            const int* pc0 = csr_src + min(base + t, end - 1);
            asm volatile("global_load_dword %0, %1, off" : "=&v"(sva) : "v"(pc0));
        }
        asm volatile("s_waitcnt vmcnt(0)");
        __builtin_amdgcn_sched_barrier(0);

        while (true) {
            int rem = min(CH, end - base);

#pragma unroll
            for (int j = 0; j < CH; ++j) {
                int jj = min(j, rem - 1);             // clamp tail to valid row
                int sj = __shfl(sva, gb + jj, 64);
                const u32x4* p = hb + (size_t)sj * TPN + t;
                asm volatile("global_load_dwordx4 %0, %1, off" : "=&v"(v[j]) : "v"(p));
            }

            int  nbase = base + CH;
            bool more  = nbase < end;
            if (more) {                               // next chunk's csr now
                const int* pc0 = csr_src + min(nbase + t, end - 1);
                asm volatile("global_load_dword %0, %1, off" : "=&v"(sva) : "v"(pc0));
                asm volatile("s_waitcnt vmcnt(1)");   // gathers only
            } else {
                asm volatile("s_waitcnt vmcnt(0)");
            }
            __builtin_amdgcn_sched_barrier(0);

#pragma unroll
            for (int j = 0; j < CH; ++j) {
                if (j < rem) {
                    unsigned int x0 = v[j][0], x1 = v[j][1], x2 = v[j][2], x3 = v[j][3];
                    a[0] += bflo(x0); a[1] += bfhi(x0);
                    a[2] += bflo(x1); a[3] += bfhi(x1);
                    a[4] += bflo(x2); a[5] += bfhi(x2);
                    a[6] += bflo(x3); a[7] += bfhi(x3);
                }
            }

            if (!more) break;
            base = nbase;
            asm volatile("s_waitcnt vmcnt(0)");       // csr for next chunk
            __builtin_amdgcn_sched_barrier(0);
        }
    }

    // ---- epilogue part 1: h1 row (bf16, post-ReLU) into padded LDS tile ----
    float dvn = dinv[node];
    float4 b0 = ((const float4*)b)[2 * t];
    float4 b1 = ((const float4*)b)[2 * t + 1];
    float o[8];
    o[0] = a[0] * dvn + b0.x; o[1] = a[1] * dvn + b0.y;
    o[2] = a[2] * dvn + b0.z; o[3] = a[3] * dvn + b0.w;
    o[4] = a[4] * dvn + b1.x; o[5] = a[5] * dvn + b1.y;
    o[6] = a[6] * dvn + b1.z; o[7] = a[7] * dvn + b1.w;
#pragma unroll
    for (int j = 0; j < 8; ++j) o[j] = fmaxf(o[j], 0.f);

    uint4 ov;
    ov.x = (unsigned int)f2bf(o[0]) | ((unsigned int)f2bf(o[1]) << 16);
    ov.y = (unsigned int)f2bf(o[2]) | ((unsigned int)f2bf(o[3]) << 16);
    ov.z = (unsigned int)f2bf(o[4]) | ((unsigned int)f2bf(o[5]) << 16);
    ov.w = (unsigned int)f2bf(o[6]) | ((unsigned int)f2bf(o[7]) << 16);
    *(uint4*)((char*)h1t + (size_t)nl * 272 + t * 16) = ov;
    if (t == 0) dl[nl] = dvn;
    __syncthreads();

    // ---- epilogue part 2: 16x128 @ 128x64 MFMA, wave wv owns cols [wv*16,+16) ----
    {
        const int wv = threadIdx.x >> 6;
        const int m  = lane & 15;
        const int q  = lane >> 4;

        f32x4 acc = {0.f, 0.f, 0.f, 0.f};
#pragma unroll
        for (int kt = 0; kt < 4; ++kt) {
            bf16x8 af  = *(const bf16x8*)((const char*)h1t + (size_t)m * 272 + q * 16 + kt * 64);
            bf16x8 bfr = *(const bf16x8*)(Wf2 + (((size_t)(kt * 4 + q) * 64) + wv * 16 + m) * 8);
            acc = __builtin_amdgcn_mfma_f32_16x16x32_bf16(af, bfr, acc, 0, 0, 0);
        }
#pragma unroll
        for (int i = 0; i < 4; ++i) {
            int nd = q * 4 + i;
            outt[nd * 64 + wv * 16 + m] = f2bf(acc[i] * dl[nd]);
        }
    }
    __syncthreads();

    // ---- cooperative coalesced store of the 16x64 bf16 tile ----
    {
        int i = threadIdx.x;
        if (i < 128) {
            int gnode = node0 + (i >> 3);
            if (gnode < n)
                ((uint4*)hs2)[(size_t)gnode * 8 + (i & 7)] = ((const uint4*)outt)[i];
        }
    }
}

// ---------------------------------------------------------------------------
// CSR gather-reduce + epilogue, bf16 features (fp32 accumulate) — layer 2
// (F=64) only now.  16-deep asm gather pipeline.
// ---------------------------------------------------------------------------
template <int F, bool RELU, bool OUTBF>
__launch_bounds__(256)
__global__ void aggregate_bf16(const int* __restrict__ row_ptr,
                               const int* __restrict__ csr_src,
                               const uint4* __restrict__ hsu,
                               const float* __restrict__ dinv,
                               const float* __restrict__ b,
                               void* __restrict__ out, int n) {
    constexpr int TPN  = F / 8;          // lanes per node (16 / 8)
    constexpr int NPB  = 256 / TPN;      // nodes per block (16 / 32)
    constexpr int CH   = 16;             // edges per pipelined chunk
    constexpr int NCSR = CH / TPN;       // csr loads/lane/chunk (1 / 2)
    int node = blockIdx.x * NPB + threadIdx.x / TPN;
    int t    = threadIdx.x % TPN;
    if (node >= n) return;
    const int lane = threadIdx.x & 63;
    const int gb   = lane & ~(TPN - 1);  // group base lane within wave

    uint4 u = hsu[(size_t)node * TPN + t];           // self-loop term
    float a[8];
    a[0] = bflo(u.x); a[1] = bfhi(u.x); a[2] = bflo(u.y); a[3] = bfhi(u.y);
    a[4] = bflo(u.z); a[5] = bfhi(u.z); a[6] = bflo(u.w); a[7] = bfhi(u.w);

    int beg = row_ptr[node], end = row_ptr[node + 1];

    if (beg < end) {
        const u32x4* hb = (const u32x4*)hsu;
        u32x4 v[CH];
        int sva, svb;
        int base = beg;

        {
            const int* pc0 = csr_src + min(base + t, end - 1);
            asm volatile("global_load_dword %0, %1, off" : "=&v"(sva) : "v"(pc0));
            if (NCSR == 2) {
                const int* pc1 = csr_src + min(base + TPN + t, end - 1);
                asm volatile("global_load_dword %0, %1, off" : "=&v"(svb) : "v"(pc1));
            }
        }
        asm volatile("s_waitcnt vmcnt(0)");
        __builtin_amdgcn_sched_barrier(0);

        while (true) {
            int rem = min(CH, end - base);

#pragma unroll
            for (int j = 0; j < CH; ++j) {
                int jj = min(j, rem - 1);            // clamp tail to a valid row
                int sj;
                if (TPN == 16) {
                    sj = __shfl(sva, gb + jj, 64);
                } else {
                    int s0 = __shfl(sva, gb + (jj & 7), 64);
                    int s1 = __shfl(svb, gb + (jj & 7), 64);
                    sj = (jj < 8) ? s0 : s1;
                }
                const u32x4* p = hb + (size_t)sj * TPN + t;
                asm volatile("global_load_dwordx4 %0, %1, off" : "=&v"(v[j]) : "v"(p));
            }

            int  nbase = base + CH;
            bool more  = nbase < end;
            if (more) {
                const int* pc0 = csr_src + min(nbase + t, end - 1);
                asm volatile("global_load_dword %0, %1, off" : "=&v"(sva) : "v"(pc0));
                if (NCSR == 2) {
                    const int* pc1 = csr_src + min(nbase + TPN + t, end - 1);
                    asm volatile("global_load_dword %0, %1, off" : "=&v"(svb) : "v"(pc1));
                }
                if (NCSR == 1) asm volatile("s_waitcnt vmcnt(1)");
                else           asm volatile("s_waitcnt vmcnt(2)");
            } else {
                asm volatile("s_waitcnt vmcnt(0)");
            }
            __builtin_amdgcn_sched_barrier(0);

#pragma unroll
            for (int j = 0; j < CH; ++j) {
                if (j < rem) {
                    unsigned int x0 = v[j][0], x1 = v[j][1], x2 = v[j][2], x3 = v[j][3];
                    a[0] += bflo(x0); a[1] += bfhi(x0);
                    a[2] += bflo(x1); a[3] += bfhi(x1);
                    a[4] += bflo(x2); a[5] += bfhi(x2);
                    a[6] += bflo(x3); a[7] += bfhi(x3);
                }
            }

            if (!more) break;
            base = nbase;
            asm volatile("s_waitcnt vmcnt(0)");
            __builtin_amdgcn_sched_barrier(0);
        }
    }

    float dvn = dinv[node];
    float4 b0 = ((const float4*)b)[2 * t];
    float4 b1 = ((const float4*)b)[2 * t + 1];
    float o[8];
    o[0] = a[0] * dvn + b0.x; o[1] = a[1] * dvn + b0.y;
    o[2] = a[2] * dvn + b0.z; o[3] = a[3] * dvn + b0.w;
    o[4] = a[4] * dvn + b1.x; o[5] = a[5] * dvn + b1.y;
    o[6] = a[6] * dvn + b1.z; o[7] = a[7] * dvn + b1.w;
    if (RELU) {
#pragma unroll
        for (int j = 0; j < 8; ++j) o[j] = fmaxf(o[j], 0.f);
    }
    if (OUTBF) {
        uint4 ov;
        ov.x = (unsigned int)f2bf(o[0]) | ((unsigned int)f2bf(o[1]) << 16);
        ov.y = (unsigned int)f2bf(o[2]) | ((unsigned int)f2bf(o[3]) << 16);
        ov.z = (unsigned int)f2bf(o[4]) | ((unsigned int)f2bf(o[5]) << 16);
        ov.w = (unsigned int)f2bf(o[6]) | ((unsigned int)f2bf(o[7]) << 16);
        ((uint4*)out)[(size_t)node * TPN + t] = ov;
    } else {
        float4* op = (float4*)out + (size_t)node * (F / 4) + 2 * t;
        op[0] = make_float4(o[0], o[1], o[2], o[3]);
        op[1] = make_float4(o[4], o[5], o[6], o[7]);
    }
}

// ---------------------------------------------------------------------------
extern "C" void kernel_launch(void* const* d_in, const int* in_sizes, int n_in,
                              void* d_out, int out_size, void* d_ws, size_t ws_size,
                              hipStream_t stream) {
    const void*  edge = d_in[0];
    const float* x    = (const float*)d_in[1];
    const float* W1   = (const float*)d_in[2];
    const float* b1   = (const float*)d_in[3];
    const float* W2   = (const float*)d_in[4];
    const float* b2   = (const float*)d_in[5];
    float* out = (float*)d_out;

    const int E    = in_sizes[0] / 2;
    const int N    = in_sizes[1] / NFEATS;
    const int NBKT = (N + SB - 1) / SB;        // 391
    const int NCH  = (E + CHUNK - 1) / CHUNK;  // 391
    const int M    = NBKT * NCH;               // histogram matrix size

    char* w = (char*)d_ws;
    auto carve = [&](size_t bytes) { void* p = w; w += (bytes + 255) & ~(size_t)255; return p; };
    int*            flag       = (int*)           carve(256);
    int*            histT      = (int*)           carve(sizeof(int) * (size_t)M);
    int*            incl       = (int*)           carve(sizeof(int) * (size_t)M);
    int*            partial    = (int*)           carve(sizeof(int) * 4096);
    int*            chunk_base = (int*)           carve(sizeof(int) * (size_t)M);
    int*            row_ptr    = (int*)           carve(sizeof(int) * ((size_t)N + 1));
    float*          dinv       = (float*)         carve(sizeof(float) * (size_t)N);
    unsigned int*   ebuf       = (unsigned int*)  carve(sizeof(int) * (size_t)E);
    int*            csr_src    = (int*)           carve(sizeof(int) * (size_t)E);
    unsigned short* Wf1        = (unsigned short*)carve(2 * (size_t)NFEATS * NHIDS);
    unsigned short* Wf2        = (unsigned short*)carve(2 * (size_t)NHIDS * NOUT);
    unsigned short* hs1        = (unsigned short*)carve(2 * (size_t)N * NHIDS);
    unsigned short* hs2        = (unsigned short*)carve(2 * (size_t)N * NOUT);

    const int B   = 256;
    const int nbS = (M + 255) / 256;           // scan blocks over histogram

    detect_kernel<<<1, 64, 0, stream>>>(edge, flag, (long long)N);

    // CSR build: chunk histograms -> scan -> LDS bucket-sort partition -> finalize
    hist_kernel<<<NCH, 512, 0, stream>>>(edge, flag, histT, E, NCH, NBKT);
    scan_block<<<nbS, 256, 0, stream>>>(histT, incl, partial, M);
    scan_partials<<<1, 512, 0, stream>>>(partial, nbS);
    finalize_scan<<<nbS, 256, 0, stream>>>(incl, histT, partial, chunk_base, M);
    scatter_chunks<<<NCH, 512, 0, stream>>>(edge, flag, chunk_base, ebuf, E, NCH, NBKT);
    bucket_finalize<<<NBKT, SB, 0, stream>>>(ebuf, chunk_base, row_ptr, dinv, csr_src,
                                             N, E, NCH, NBKT);

    // pack both weights into B-frag order (one launch)
    w_pack<<<(128 * 128 + B - 1) / B, B, 0, stream>>>(W1, Wf1, W2, Wf2);

    // ---- layer 1 GEMM ----
    gemm_mfma<NHIDS, true><<<(N + 127) / 128, B, 0, stream>>>(x, Wf1, dinv, hs1, N);

    // ---- fused: layer-1 aggregate + ReLU + layer-2 GEMM -> hs2 ----
    aggregate_fused_l1<<<(N + 15) / 16, B, 0, stream>>>(
        row_ptr, csr_src, (const uint4*)hs1, dinv, b1, Wf2, hs2, N);

    // ---- layer-2 aggregate -> out ----
    {
        constexpr int NPB = 256 / (NOUT / 8);    // 32 nodes per block
        aggregate_bf16<NOUT, false, false><<<(N + NPB - 1) / NPB, B, 0, stream>>>(
            row_ptr, csr_src, (const uint4*)hs2, dinv, b2, out, N);
    }
}

// Round 5
// 248.818 us; speedup vs baseline: 1.1228x; 1.0127x over previous
//
#include <hip/hip_runtime.h>
#include <cstdint>
#include <cstddef>

#define NFEATS 128
#define NHIDS  128
#define NOUT   64
#define SB     256    // nodes per bucket (dst >> 8)
#define CHUNK  4096   // edges per chunk in the radix partition

using bf16x8 = __attribute__((ext_vector_type(8))) short;
using f32x4  = __attribute__((ext_vector_type(4))) float;
using u32x4  = __attribute__((ext_vector_type(4))) unsigned int;

__device__ inline unsigned short f2bf(float f) {           // round-to-nearest-even
    union { float f; unsigned int u; } v; v.f = f;
    unsigned int r = (v.u + 0x7FFFu + ((v.u >> 16) & 1u)) >> 16;
    return (unsigned short)r;
}
__device__ inline float bflo(unsigned int u) { return __uint_as_float(u << 16); }
__device__ inline float bfhi(unsigned int u) { return __uint_as_float(u & 0xFFFF0000u); }

// ---------------------------------------------------------------------------
// Launch 1: edge dtype detect (block 0) + weight pack (blocks 1..64).
// ---------------------------------------------------------------------------
__global__ void detect_wpack(const void* __restrict__ p, int* __restrict__ flag,
                             long long n_nodes,
                             const float* __restrict__ W1, unsigned short* __restrict__ Wf1,
                             const float* __restrict__ W2, unsigned short* __restrict__ Wf2) {
    if (blockIdx.x == 0) {
        if (threadIdx.x < 64) {
            const long long* q = (const long long*)p;
            long long v = q[threadIdx.x];
            int bad = (v < 0 || v >= n_nodes) ? 1 : 0;
            unsigned long long m = __ballot(bad);
            if (threadIdx.x == 0) *flag = (m != 0ULL) ? 1 : 0;
        }
        return;
    }
    int i = (blockIdx.x - 1) * 256 + threadIdx.x;      // [0, 16384)
    if (i < 128 * 128) {                               // W1: [128][128]
        int k = i >> 7, n = i & 127;
        Wf1[(((k >> 3) * 128) + n) * 8 + (k & 7)] = f2bf(W1[i]);
    }
    if (i < 128 * 64) {                                // W2: [128][64]
        int k = i >> 6, n = i & 63;
        Wf2[(((k >> 3) * 64) + n) * 8 + (k & 7)] = f2bf(W2[i]);
    }
}

// ---------------------------------------------------------------------------
// Phase 1a: per-(chunk,bucket) histogram. histT[b*nch + c].
// ---------------------------------------------------------------------------
__global__ __launch_bounds__(512)
void hist_kernel(const void* __restrict__ edges, const int* __restrict__ flag,
                 int* __restrict__ histT, int ne, int nch, int nbkt) {
    __shared__ int h[1024];
    int c = blockIdx.x, t = threadIdx.x;              // blockDim = 512
    for (int i = t; i < nbkt; i += 512) h[i] = 0;
    __syncthreads();
    int beg = c * CHUNK, end = min(ne, beg + CHUNK);
    bool is32 = (*flag != 0);
    for (int i = beg + t; i < end; i += 512) {
        int d = is32 ? ((const int*)edges)[ne + i]
                     : (int)((const long long*)edges)[ne + i];
        atomicAdd(&h[d >> 8], 1);
    }
    __syncthreads();
    for (int i = t; i < nbkt; i += 512)
        histT[i * nch + c] = h[i];
}

// ---------------------------------------------------------------------------
// Exclusive scan over histT.  chunk_base computed inline by consumers:
// CB(i) = partial[i>>8] + incl[i] - histT[i].
// ---------------------------------------------------------------------------
__global__ void scan_block(const int* __restrict__ v, int* __restrict__ incl,
                           int* __restrict__ partial, int n) {
    __shared__ int sh[256];
    int t = threadIdx.x;
    int i = blockIdx.x * 256 + t;
    sh[t] = (i < n) ? v[i] : 0;
    __syncthreads();
    for (int off = 1; off < 256; off <<= 1) {
        int add = (t >= off) ? sh[t - off] : 0;
        __syncthreads();
        sh[t] += add;
        __syncthreads();
    }
    if (i < n) incl[i] = sh[t];
    if (t == 255) partial[blockIdx.x] = sh[255];
}

__global__ void scan_partials(int* partial, int nb) {
    __shared__ int sh[512];
    __shared__ int carry;
    int t = threadIdx.x;
    if (t == 0) carry = 0;
    __syncthreads();
    for (int base = 0; base < nb; base += 512) {
        int idx = base + t;
        sh[t] = (idx < nb) ? partial[idx] : 0;
        __syncthreads();
        for (int off = 1; off < 512; off <<= 1) {
            int add = (t >= off) ? sh[t - off] : 0;
            __syncthreads();
            sh[t] += add;
            __syncthreads();
        }
        int excl = carry + ((t == 0) ? 0 : sh[t - 1]);
        if (idx < nb) partial[idx] = excl;
        __syncthreads();
        if (t == 0) carry += sh[511];
        __syncthreads();
    }
}

// ---------------------------------------------------------------------------
// Phase 1b: LDS bucket sort + coalesced writes (chunk_base inline).
// ---------------------------------------------------------------------------
__global__ __launch_bounds__(512)
void scatter_chunks(const void* __restrict__ edges, const int* __restrict__ flag,
                    const int* __restrict__ histT, const int* __restrict__ incl,
                    const int* __restrict__ partial,
                    unsigned int* __restrict__ ebuf,
                    int ne, int nch, int nbkt) {
    __shared__ int cnt[512];
    __shared__ int cursor[512];
    __shared__ int delta[512];
    __shared__ unsigned int   srt[CHUNK];            // 16 KB
    __shared__ unsigned short bkl[CHUNK];            // 8 KB
    int c = blockIdx.x, t = threadIdx.x;              // blockDim = 512
    if (t < nbkt) cnt[t] = 0;
    int cb = 0;
    if (t < nbkt) {
        int idx = t * nch + c;
        cb = partial[idx >> 8] + incl[idx] - histT[idx];
    }
    __syncthreads();

    int beg = c * CHUNK, end = min(ne, beg + CHUNK);
    int nloc = end - beg;
    bool is32 = (*flag != 0);

    unsigned int rec[8];
    int bk[8];
#pragma unroll
    for (int r = 0; r < 8; ++r) {
        int i = beg + t + r * 512;
        bk[r] = -1;
        if (i < end) {
            int s, d;
            if (is32) {
                s = ((const int*)edges)[i];
                d = ((const int*)edges)[ne + i];
            } else {
                s = (int)((const long long*)edges)[i];
                d = (int)((const long long*)edges)[ne + i];
            }
            rec[r] = ((unsigned int)s << 8) | (unsigned int)(d & (SB - 1));
            bk[r]  = d >> 8;
            atomicAdd(&cnt[bk[r]], 1);
        }
    }
    __syncthreads();

    int v0 = (t < nbkt) ? cnt[t] : 0;
    cursor[t] = v0;
    __syncthreads();
    for (int off = 1; off < 512; off <<= 1) {
        int add = (t >= off) ? cursor[t - off] : 0;
        __syncthreads();
        cursor[t] += add;
        __syncthreads();
    }
    int inc = cursor[t];
    __syncthreads();
    int lb = inc - v0;
    cursor[t] = lb;
    if (t < nbkt) delta[t] = cb - lb;
    __syncthreads();

#pragma unroll
    for (int r = 0; r < 8; ++r) {
        if (bk[r] >= 0) {
            int pos = atomicAdd(&cursor[bk[r]], 1);
            srt[pos] = rec[r];
            bkl[pos] = (unsigned short)bk[r];
        }
    }
    __syncthreads();

    for (int i = t; i < nloc; i += 512)
        ebuf[delta[bkl[i]] + i] = srt[i];
}

// ---------------------------------------------------------------------------
// Phase 2: per-bucket CSR finalize; LDS-staged coalesced csr_src write;
// chunk_base inline.
// ---------------------------------------------------------------------------
__global__ void bucket_finalize(const unsigned int* __restrict__ ebuf,
                                const int* __restrict__ histT, const int* __restrict__ inclG,
                                const int* __restrict__ partial,
                                int* __restrict__ row_ptr, float* __restrict__ dinv,
                                int* __restrict__ csr_src,
                                int n, int e, int nch, int nbkt) {
    __shared__ int deg[SB];
    __shared__ int incl[SB];
    __shared__ int cur[SB];
    __shared__ int stage[4608];                        // 18 KB staging
    __shared__ int sbase, sbend;
    int b = blockIdx.x, t = threadIdx.x;               // blockDim = SB = 256
    int node0 = b * SB;
    int nn = min(SB, n - node0);
    if (t == 0) {
        int i0 = b * nch;
        sbase = partial[i0 >> 8] + inclG[i0] - histT[i0];
        if (b == nbkt - 1) sbend = e;
        else {
            int i1 = (b + 1) * nch;
            sbend = partial[i1 >> 8] + inclG[i1] - histT[i1];
        }
    }
    deg[t] = 0;
    __syncthreads();
    int base = sbase, bend = sbend;

    for (int i = base + t; i < bend; i += SB)
        atomicAdd(&deg[ebuf[i] & (SB - 1)], 1);
    __syncthreads();

    incl[t] = deg[t];
    __syncthreads();
    for (int off = 1; off < SB; off <<= 1) {
        int add = (t >= off) ? incl[t - off] : 0;
        __syncthreads();
        incl[t] += add;
        __syncthreads();
    }
    int lrow = base + incl[t] - deg[t];
    cur[t] = lrow - base;                              // local cursor
    if (t < nn) {
        row_ptr[node0 + t] = lrow;
        dinv[node0 + t]    = rsqrtf((float)(deg[t] + 1));
    }
    if (b == nbkt - 1 && t == 0) row_ptr[n] = e;
    __syncthreads();

    int cntE = bend - base;
    if (cntE <= 4608) {
        for (int i = base + t; i < bend; i += SB) {
            unsigned int r = ebuf[i];
            int pos = atomicAdd(&cur[r & (SB - 1)], 1);
            stage[pos] = (int)(r >> 8);
        }
        __syncthreads();
        for (int i = t; i < cntE; i += SB)             // coalesced linear store
            csr_src[base + i] = stage[i];
    } else {
        for (int i = base + t; i < bend; i += SB) {
            unsigned int r = ebuf[i];
            int pos = atomicAdd(&cur[r & (SB - 1)], 1);
            csr_src[base + pos] = (int)(r >> 8);
        }
    }
}

// ---------------------------------------------------------------------------
// MFMA GEMM (needs dinv, so runs after bucket_finalize): 256 threads.
// ---------------------------------------------------------------------------
template <int NC, bool F32IN>
__launch_bounds__(256)
__global__ void gemm_mfma(const void* __restrict__ Xin,
                          const unsigned short* __restrict__ Wf,
                          const float* __restrict__ dinv,
                          unsigned short* __restrict__ hs, int nrows) {
    constexpr int K = 128;
    __shared__ __align__(16) unsigned short Xl[16 * 128 * 8];   // 32 KB

    const int tid  = threadIdx.x;
    const int row0 = blockIdx.x * 128;

    for (int i = tid; i < 128 * 32; i += 256) {        // stage X tile
        int r  = i >> 5;
        int c4 = i & 31;
        int gr = row0 + r;
        ushort4 v = make_ushort4(0, 0, 0, 0);
        if (gr < nrows) {
            if (F32IN) {
                float4 f = ((const float4*)((const float*)Xin + (size_t)gr * K))[c4];
                v.x = f2bf(f.x); v.y = f2bf(f.y); v.z = f2bf(f.z); v.w = f2bf(f.w);
            } else {
                v = ((const ushort4*)((const unsigned short*)Xin + (size_t)gr * K))[c4];
            }
        }
        int k   = c4 * 4;
        int grp = k >> 3;                              // kt*4 + q
        int j0  = k & 7;                               // 0 or 4
        *(ushort4*)(Xl + ((size_t)grp * 128 + r) * 8 + j0) = v;
    }
    __syncthreads();

    const int wv   = tid >> 6;
    const int lane = tid & 63;
    const int m    = lane & 15;
    const int q    = lane >> 4;

    bf16x8 af[2][4];
#pragma unroll
    for (int h = 0; h < 2; ++h)
#pragma unroll
        for (int kt = 0; kt < 4; ++kt)
            af[h][kt] = *(const bf16x8*)(Xl + (((kt * 4 + q) * 128) + h * 64 + wv * 16 + m) * 8);

    int   rbase[2];
    float dv[2][4];
#pragma unroll
    for (int h = 0; h < 2; ++h) {
        rbase[h] = row0 + h * 64 + wv * 16 + q * 4;
#pragma unroll
        for (int i = 0; i < 4; ++i)
            dv[h][i] = (rbase[h] + i < nrows) ? dinv[rbase[h] + i] : 0.f;
    }

#pragma unroll
    for (int nt = 0; nt < NC / 16; ++nt) {
        bf16x8 bfr[4];
#pragma unroll
        for (int kt = 0; kt < 4; ++kt)
            bfr[kt] = *(const bf16x8*)(Wf + (((size_t)(kt * 4 + q) * NC) + nt * 16 + m) * 8);
#pragma unroll
        for (int h = 0; h < 2; ++h) {
            f32x4 acc = {0.f, 0.f, 0.f, 0.f};
#pragma unroll
            for (int kt = 0; kt < 4; ++kt)
                acc = __builtin_amdgcn_mfma_f32_16x16x32_bf16(af[h][kt], bfr[kt], acc, 0, 0, 0);
#pragma unroll
            for (int i = 0; i < 4; ++i) {
                int g = rbase[h] + i;
                if (g < nrows)
                    hs[(size_t)g * NC + nt * 16 + m] = f2bf(acc[i] * dv[h][i]);
            }
        }
    }
}

// ---------------------------------------------------------------------------
// FUSED layer-1 aggregate + layer-2 GEMM (at the random-gather fetch-path
// floor: 186 MB FETCH at ~3.15 TB/s).
// ---------------------------------------------------------------------------
__launch_bounds__(256)
__global__ void aggregate_fused_l1(const int* __restrict__ row_ptr,
                                   const int* __restrict__ csr_src,
                                   const uint4* __restrict__ hsu,
                                   const float* __restrict__ dinv,
                                   const float* __restrict__ b,
                                   const unsigned short* __restrict__ Wf2,
                                   unsigned short* __restrict__ hs2, int n) {
    constexpr int TPN = 16;
    constexpr int NPB = 16;
    constexpr int CH  = 16;

    __shared__ __align__(16) unsigned short h1t[16 * 136];   // 272 B/row
    __shared__ float dl[16];
    __shared__ __align__(16) unsigned short outt[16 * 64];   // 2 KB

    const int node0 = blockIdx.x * NPB;
    const int nl    = threadIdx.x / TPN;
    const int t     = threadIdx.x % TPN;
    const int node  = min(node0 + nl, n - 1);
    const int lane  = threadIdx.x & 63;
    const int gb    = lane & ~(TPN - 1);

    uint4 u = hsu[(size_t)node * TPN + t];            // self-loop term
    float a[8];
    a[0] = bflo(u.x); a[1] = bfhi(u.x); a[2] = bflo(u.y); a[3] = bfhi(u.y);
    a[4] = bflo(u.z); a[5] = bfhi(u.z); a[6] = bflo(u.w); a[7] = bfhi(u.w);

    int beg = row_ptr[node], end = row_ptr[node + 1];

    if (beg < end) {
        const u32x4* hb = (const u32x4*)hsu;
        u32x4 v[CH];
        int sva;
        int base = beg;

        {
            const int* pc0 = csr_src + min(base + t, end - 1);
            asm volatile("global_load_dword %0, %1, off" : "=&v"(sva) : "v"(pc0));
        }
        asm volatile("s_waitcnt vmcnt(0)");
        __builtin_amdgcn_sched_barrier(0);

        while (true) {
            int rem = min(CH, end - base);

#pragma unroll
            for (int j = 0; j < CH; ++j) {
                int jj = min(j, rem - 1);
                int sj = __shfl(sva, gb + jj, 64);
                const u32x4* p = hb + (size_t)sj * TPN + t;
                asm volatile("global_load_dwordx4 %0, %1, off" : "=&v"(v[j]) : "v"(p));
            }

            int  nbase = base + CH;
            bool more  = nbase < end;
            if (more) {
                const int* pc0 = csr_src + min(nbase + t, end - 1);
                asm volatile("global_load_dword %0, %1, off" : "=&v"(sva) : "v"(pc0));
                asm volatile("s_waitcnt vmcnt(1)");
            } else {
                asm volatile("s_waitcnt vmcnt(0)");
            }
            __builtin_amdgcn_sched_barrier(0);

#pragma unroll
            for (int j = 0; j < CH; ++j) {
                if (j < rem) {
                    unsigned int x0 = v[j][0], x1 = v[j][1], x2 = v[j][2], x3 = v[j][3];
                    a[0] += bflo(x0); a[1] += bfhi(x0);
                    a[2] += bflo(x1); a[3] += bfhi(x1);
                    a[4] += bflo(x2); a[5] += bfhi(x2);
                    a[6] += bflo(x3); a[7] += bfhi(x3);
                }
            }

            if (!more) break;
            base = nbase;
            asm volatile("s_waitcnt vmcnt(0)");
            __builtin_amdgcn_sched_barrier(0);
        }
    }

    float dvn = dinv[node];
    float4 b0 = ((const float4*)b)[2 * t];
    float4 b1 = ((const float4*)b)[2 * t + 1];
    float o[8];
    o[0] = a[0] * dvn + b0.x; o[1] = a[1] * dvn + b0.y;
    o[2] = a[2] * dvn + b0.z; o[3] = a[3] * dvn + b0.w;
    o[4] = a[4] * dvn + b1.x; o[5] = a[5] * dvn + b1.y;
    o[6] = a[6] * dvn + b1.z; o[7] = a[7] * dvn + b1.w;
#pragma unroll
    for (int j = 0; j < 8; ++j) o[j] = fmaxf(o[j], 0.f);

    uint4 ov;
    ov.x = (unsigned int)f2bf(o[0]) | ((unsigned int)f2bf(o[1]) << 16);
    ov.y = (unsigned int)f2bf(o[2]) | ((unsigned int)f2bf(o[3]) << 16);
    ov.z = (unsigned int)f2bf(o[4]) | ((unsigned int)f2bf(o[5]) << 16);
    ov.w = (unsigned int)f2bf(o[6]) | ((unsigned int)f2bf(o[7]) << 16);
    *(uint4*)((char*)h1t + (size_t)nl * 272 + t * 16) = ov;
    if (t == 0) dl[nl] = dvn;
    __syncthreads();

    {
        const int wv = threadIdx.x >> 6;
        const int m  = lane & 15;
        const int q  = lane >> 4;

        f32x4 acc = {0.f, 0.f, 0.f, 0.f};
#pragma unroll
        for (int kt = 0; kt < 4; ++kt) {
            bf16x8 af  = *(const bf16x8*)((const char*)h1t + (size_t)m * 272 + q * 16 + kt * 64);
            bf16x8 bfr = *(const bf16x8*)(Wf2 + (((size_t)(kt * 4 + q) * 64) + wv * 16 + m) * 8);
            acc = __builtin_amdgcn_mfma_f32_16x16x32_bf16(af, bfr, acc, 0, 0, 0);
        }
#pragma unroll
        for (int i = 0; i < 4; ++i) {
            int nd = q * 4 + i;
            outt[nd * 64 + wv * 16 + m] = f2bf(acc[i] * dl[nd]);
        }
    }
    __syncthreads();

    {
        int i = threadIdx.x;
        if (i < 128) {
            int gnode = node0 + (i >> 3);
            if (gnode < n)
                ((uint4*)hs2)[(size_t)gnode * 8 + (i & 7)] = ((const uint4*)outt)[i];
        }
    }
}

// ---------------------------------------------------------------------------
// Layer-2 aggregate (F=64), 16-deep asm gather pipeline.
// ---------------------------------------------------------------------------
template <int F, bool RELU, bool OUTBF>
__launch_bounds__(256)
__global__ void aggregate_bf16(const int* __restrict__ row_ptr,
                               const int* __restrict__ csr_src,
                               const uint4* __restrict__ hsu,
                               const float* __restrict__ dinv,
                               const float* __restrict__ b,
                               void* __restrict__ out, int n) {
    constexpr int TPN  = F / 8;
    constexpr int NPB  = 256 / TPN;
    constexpr int CH   = 16;
    constexpr int NCSR = CH / TPN;
    int node = blockIdx.x * NPB + threadIdx.x / TPN;
    int t    = threadIdx.x % TPN;
    if (node >= n) return;
    const int lane = threadIdx.x & 63;
    const int gb   = lane & ~(TPN - 1);

    uint4 u = hsu[(size_t)node * TPN + t];
    float a[8];
    a[0] = bflo(u.x); a[1] = bfhi(u.x); a[2] = bflo(u.y); a[3] = bfhi(u.y);
    a[4] = bflo(u.z); a[5] = bfhi(u.z); a[6] = bflo(u.w); a[7] = bfhi(u.w);

    int beg = row_ptr[node], end = row_ptr[node + 1];

    if (beg < end) {
        const u32x4* hb = (const u32x4*)hsu;
        u32x4 v[CH];
        int sva, svb;
        int base = beg;

        {
            const int* pc0 = csr_src + min(base + t, end - 1);
            asm volatile("global_load_dword %0, %1, off" : "=&v"(sva) : "v"(pc0));
            if (NCSR == 2) {
                const int* pc1 = csr_src + min(base + TPN + t, end - 1);
                asm volatile("global_load_dword %0, %1, off" : "=&v"(svb) : "v"(pc1));
            }
        }
        asm volatile("s_waitcnt vmcnt(0)");
        __builtin_amdgcn_sched_barrier(0);

        while (true) {
            int rem = min(CH, end - base);

#pragma unroll
            for (int j = 0; j < CH; ++j) {
                int jj = min(j, rem - 1);
                int sj;
                if (TPN == 16) {
                    sj = __shfl(sva, gb + jj, 64);
                } else {
                    int s0 = __shfl(sva, gb + (jj & 7), 64);
                    int s1 = __shfl(svb, gb + (jj & 7), 64);
                    sj = (jj < 8) ? s0 : s1;
                }
                const u32x4* p = hb + (size_t)sj * TPN + t;
                asm volatile("global_load_dwordx4 %0, %1, off" : "=&v"(v[j]) : "v"(p));
            }

            int  nbase = base + CH;
            bool more  = nbase < end;
            if (more) {
                const int* pc0 = csr_src + min(nbase + t, end - 1);
                asm volatile("global_load_dword %0, %1, off" : "=&v"(sva) : "v"(pc0));
                if (NCSR == 2) {
                    const int* pc1 = csr_src + min(nbase + TPN + t, end - 1);
                    asm volatile("global_load_dword %0, %1, off" : "=&v"(svb) : "v"(pc1));
                }
                if (NCSR == 1) asm volatile("s_waitcnt vmcnt(1)");
                else           asm volatile("s_waitcnt vmcnt(2)");
            } else {
                asm volatile("s_waitcnt vmcnt(0)");
            }
            __builtin_amdgcn_sched_barrier(0);

#pragma unroll
            for (int j = 0; j < CH; ++j) {
                if (j < rem) {
                    unsigned int x0 = v[j][0], x1 = v[j][1], x2 = v[j][2], x3 = v[j][3];
                    a[0] += bflo(x0); a[1] += bfhi(x0);
                    a[2] += bflo(x1); a[3] += bfhi(x1);
                    a[4] += bflo(x2); a[5] += bfhi(x2);
                    a[6] += bflo(x3); a[7] += bfhi(x3);
                }
            }

            if (!more) break;
            base = nbase;
            asm volatile("s_waitcnt vmcnt(0)");
            __builtin_amdgcn_sched_barrier(0);
        }
    }

    float dvn = dinv[node];
    float4 b0 = ((const float4*)b)[2 * t];
    float4 b1 = ((const float4*)b)[2 * t + 1];
    float o[8];
    o[0] = a[0] * dvn + b0.x; o[1] = a[1] * dvn + b0.y;
    o[2] = a[2] * dvn + b0.z; o[3] = a[3] * dvn + b0.w;
    o[4] = a[4] * dvn + b1.x; o[5] = a[5] * dvn + b1.y;
    o[6] = a[6] * dvn + b1.z; o[7] = a[7] * dvn + b1.w;
    if (RELU) {
#pragma unroll
        for (int j = 0; j < 8; ++j) o[j] = fmaxf(o[j], 0.f);
    }
    if (OUTBF) {
        uint4 ov;
        ov.x = (unsigned int)f2bf(o[0]) | ((unsigned int)f2bf(o[1]) << 16);
        ov.y = (unsigned int)f2bf(o[2]) | ((unsigned int)f2bf(o[3]) << 16);
        ov.z = (unsigned int)f2bf(o[4]) | ((unsigned int)f2bf(o[5]) << 16);
        ov.w = (unsigned int)f2bf(o[6]) | ((unsigned int)f2bf(o[7]) << 16);
        ((uint4*)out)[(size_t)node * TPN + t] = ov;
    } else {
        float4* op = (float4*)out + (size_t)node * (F / 4) + 2 * t;
        op[0] = make_float4(o[0], o[1], o[2], o[3]);
        op[1] = make_float4(o[4], o[5], o[6], o[7]);
    }
}

// ---------------------------------------------------------------------------
extern "C" void kernel_launch(void* const* d_in, const int* in_sizes, int n_in,
                              void* d_out, int out_size, void* d_ws, size_t ws_size,
                              hipStream_t stream) {
    const void*  edge = d_in[0];
    const float* x    = (const float*)d_in[1];
    const float* W1   = (const float*)d_in[2];
    const float* b1   = (const float*)d_in[3];
    const float* W2   = (const float*)d_in[4];
    const float* b2   = (const float*)d_in[5];
    float* out = (float*)d_out;

    const int E    = in_sizes[0] / 2;
    const int N    = in_sizes[1] / NFEATS;
    const int NBKT = (N + SB - 1) / SB;        // 391
    const int NCH  = (E + CHUNK - 1) / CHUNK;  // 391
    const int M    = NBKT * NCH;

    char* w = (char*)d_ws;
    auto carve = [&](size_t bytes) { void* p = w; w += (bytes + 255) & ~(size_t)255; return p; };
    int*            flag       = (int*)           carve(256);
    int*            histT      = (int*)           carve(sizeof(int) * (size_t)M);
    int*            incl       = (int*)           carve(sizeof(int) * (size_t)M);
    int*            partial    = (int*)           carve(sizeof(int) * 4096);
    int*            row_ptr    = (int*)           carve(sizeof(int) * ((size_t)N + 1));
    float*          dinv       = (float*)         carve(sizeof(float) * (size_t)N);
    unsigned int*   ebuf       = (unsigned int*)  carve(sizeof(int) * (size_t)E);
    int*            csr_src    = (int*)           carve(sizeof(int) * (size_t)E);
    unsigned short* Wf1        = (unsigned short*)carve(2 * (size_t)NFEATS * NHIDS);
    unsigned short* Wf2        = (unsigned short*)carve(2 * (size_t)NHIDS * NOUT);
    unsigned short* hs1        = (unsigned short*)carve(2 * (size_t)N * NHIDS);
    unsigned short* hs2        = (unsigned short*)carve(2 * (size_t)N * NOUT);

    const int nbS = (M + 255) / 256;

    // 1. detect + weight pack (fused)
    detect_wpack<<<65, 256, 0, stream>>>(edge, flag, (long long)N, W1, Wf1, W2, Wf2);

    // 2-5. CSR build (finalize_scan eliminated; chunk_base computed inline)
    hist_kernel<<<NCH, 512, 0, stream>>>(edge, flag, histT, E, NCH, NBKT);
    scan_block<<<nbS, 256, 0, stream>>>(histT, incl, partial, M);
    scan_partials<<<1, 512, 0, stream>>>(partial, nbS);
    scatter_chunks<<<NCH, 512, 0, stream>>>(edge, flag, histT, incl, partial,
                                            ebuf, E, NCH, NBKT);
    bucket_finalize<<<NBKT, SB, 0, stream>>>(ebuf, histT, incl, partial,
                                             row_ptr, dinv, csr_src, N, E, NCH, NBKT);

    // 6. layer-1 GEMM (needs dinv)
    gemm_mfma<NHIDS, true><<<(N + 127) / 128, 256, 0, stream>>>(x, Wf1, dinv, hs1, N);

    // 7. fused: layer-1 aggregate + ReLU + layer-2 GEMM -> hs2
    aggregate_fused_l1<<<(N + 15) / 16, 256, 0, stream>>>(
        row_ptr, csr_src, (const uint4*)hs1, dinv, b1, Wf2, hs2, N);

    // 8. layer-2 aggregate -> out
    {
        constexpr int NPB = 256 / (NOUT / 8);
        aggregate_bf16<NOUT, false, false><<<(N + NPB - 1) / NPB, 256, 0, stream>>>(
            row_ptr, csr_src, (const uint4*)hs2, dinv, b2, out, N);
    }
}